// Round 1
// baseline (1013.218 us; speedup 1.0000x reference)
//
#include <hip/hip_runtime.h>
#include <math.h>

#define Bn 8
#define Nn 4096
#define Dn 256
#define En 65536

__device__ __forceinline__ float4 ld4(const float* p) { return *(const float4*)p; }

// ---------------- edge CSR build (by destination v, valid edges only) ----------------

__global__ __launch_bounds__(256) void hist_kernel(const int* __restrict__ ei,
                                                   const int* __restrict__ mask,
                                                   int* __restrict__ cnt) {
    int idx = blockIdx.x * 256 + threadIdx.x;   // [0, B*E)
    int b = idx >> 16;                          // E = 65536
    int e = idx & 65535;
    const int* eb = ei + (size_t)b * 2 * En;
    int u = eb[e];
    int v = eb[En + e];
    const int* mb = mask + b * Nn;
    if (mb[u] > 0 && mb[v] > 0) atomicAdd(&cnt[b * Nn + v], 1);
}

__global__ __launch_bounds__(256) void scan_kernel(const int* __restrict__ cnt,
                                                   int* __restrict__ off,
                                                   int* __restrict__ cursor) {
    int b = blockIdx.x, t = threadIdx.x;
    __shared__ int chunk[256];
    int local[16];
    int s = 0;
    int base = b * Nn + t * 16;
#pragma unroll
    for (int i = 0; i < 16; i++) { local[i] = cnt[base + i]; s += local[i]; }
    chunk[t] = s;
    __syncthreads();
    for (int st = 1; st < 256; st <<= 1) {
        int v = (t >= st) ? chunk[t - st] : 0;
        __syncthreads();
        chunk[t] += v;
        __syncthreads();
    }
    int run = chunk[t] - s;   // exclusive chunk base
    int ob = b * (Nn + 1) + t * 16;
#pragma unroll
    for (int i = 0; i < 16; i++) {
        off[ob + i] = run;
        cursor[base + i] = run;
        run += local[i];
    }
    if (t == 255) off[b * (Nn + 1) + Nn] = run;
}

__global__ __launch_bounds__(256) void fill_kernel(const int* __restrict__ ei,
                                                   const int* __restrict__ mask,
                                                   const float* __restrict__ ew,
                                                   int* __restrict__ cursor,
                                                   int* __restrict__ csr_u,
                                                   float* __restrict__ csr_w) {
    int idx = blockIdx.x * 256 + threadIdx.x;
    int b = idx >> 16;
    int e = idx & 65535;
    const int* eb = ei + (size_t)b * 2 * En;
    int u = eb[e];
    int v = eb[En + e];
    const int* mb = mask + b * Nn;
    if (mb[u] > 0 && mb[v] > 0) {
        int pos = atomicAdd(&cursor[b * Nn + v], 1);
        csr_u[(size_t)b * En + pos] = u;
        csr_w[(size_t)b * En + pos] = ew[(size_t)b * En + e];
    }
}

// ---------------- m = x @ W  (M=32768, N=256, K=256, fp32) ----------------

__global__ __launch_bounds__(256) void gemm_m_kernel(const float* __restrict__ X,
                                                     const float* __restrict__ W,
                                                     float* __restrict__ Mo) {
    __shared__ float As[16][68];   // [k][m] transposed; 68*4=272B row, 16B-aligned
    __shared__ float Bs[16][68];   // [k][n]
    int t = threadIdx.x;
    int row0 = blockIdx.x * 64, col0 = blockIdx.y * 64;
    int tx = t & 15, ty = t >> 4;
    int ar = t >> 2, ak = (t & 3) * 4;
    int bk = t >> 4, bc = (t & 15) * 4;
    float acc[4][4] = {};
    for (int k0 = 0; k0 < 256; k0 += 16) {
        float4 av = ld4(&X[(size_t)(row0 + ar) * 256 + k0 + ak]);
        float4 bv = ld4(&W[(size_t)(k0 + bk) * 256 + col0 + bc]);
        __syncthreads();
        As[ak + 0][ar] = av.x; As[ak + 1][ar] = av.y;
        As[ak + 2][ar] = av.z; As[ak + 3][ar] = av.w;
        *(float4*)&Bs[bk][bc] = bv;
        __syncthreads();
#pragma unroll
        for (int kk = 0; kk < 16; kk++) {
            float4 a = ld4(&As[kk][ty * 4]);
            float4 bb = ld4(&Bs[kk][tx * 4]);
            const float* ap = &a.x;
            const float* bp = &bb.x;
#pragma unroll
            for (int i = 0; i < 4; i++)
#pragma unroll
                for (int j = 0; j < 4; j++) acc[i][j] += ap[i] * bp[j];
        }
    }
#pragma unroll
    for (int i = 0; i < 4; i++) {
        float4 o = make_float4(acc[i][0], acc[i][1], acc[i][2], acc[i][3]);
        *(float4*)&Mo[(size_t)(row0 + ty * 4 + i) * 256 + col0 + tx * 4] = o;
    }
}

// ---------------- agg[b,n,:] = sum_{edges -> n} w * m[b,u,:]  (one wave per node) -----

__global__ __launch_bounds__(256) void agg_kernel(const float* __restrict__ M,
                                                  const int* __restrict__ off,
                                                  const int* __restrict__ csr_u,
                                                  const float* __restrict__ csr_w,
                                                  float* __restrict__ agg) {
    int wave = threadIdx.x >> 6, lane = threadIdx.x & 63;
    int g = blockIdx.x * 4 + wave;        // [0, B*N)
    int b = g >> 12, n = g & 4095;
    int s = off[b * (Nn + 1) + n];
    int e = off[b * (Nn + 1) + n + 1];
    const int* cu = csr_u + (size_t)b * En;
    const float* cw = csr_w + (size_t)b * En;
    const float4* Mb = (const float4*)(M + (size_t)b * Nn * 256);
    float4 acc = make_float4(0.f, 0.f, 0.f, 0.f);
    for (int j = s; j < e; j++) {
        int u = cu[j];
        float w = cw[j];
        float4 mv = Mb[(size_t)u * 64 + lane];
        acc.x += w * mv.x; acc.y += w * mv.y;
        acc.z += w * mv.z; acc.w += w * mv.w;
    }
    *(float4*)&agg[(size_t)g * 256 + lane * 4] = acc;
}

// ---------------- fused GRU: 6 GEMM tiles (r/z/n x ih/hh) + gates + mask -------------
// Tile: 64 rows x 64 cols, BK=32, 256 threads, 4x4 micro per matrix.
// LDS layout: per (c,k): offset c*32 + (k&3) + 4*((k>>2) ^ ((c>>2)&7))  -> 2-way max.

#define GPOS(c, kq) ((c) * 32 + 4 * ((kq) ^ (((c) >> 2) & 7)))

__global__ __launch_bounds__(256) void gru_kernel(const float* __restrict__ agg,
                                                  const float* __restrict__ X,
                                                  const float* __restrict__ Wih,
                                                  const float* __restrict__ Whh,
                                                  const float* __restrict__ bih,
                                                  const float* __restrict__ bhh,
                                                  const int* __restrict__ mask,
                                                  float* __restrict__ out) {
    __shared__ float Aag[2048];
    __shared__ float Ahh[2048];
    __shared__ float Bi[3][2048];
    __shared__ float Bh[3][2048];
    int t = threadIdx.x;
    int row0 = blockIdx.x * 64, col0 = blockIdx.y * 64;
    int tx = t & 15, ty = t >> 4;
    int c = t >> 2;            // load row/col 0..63
    int kb = (t & 3) * 8;      // 0,8,16,24
    int q0 = kb >> 2, q1 = q0 + 1;
    float acc_i[3][4][4] = {};
    float acc_h[3][4][4] = {};
    for (int k0 = 0; k0 < 256; k0 += 32) {
        const float* pA = agg + (size_t)(row0 + c) * 256 + k0 + kb;
        const float* pH = X + (size_t)(row0 + c) * 256 + k0 + kb;
        float4 a0 = ld4(pA), a1 = ld4(pA + 4);
        float4 h0 = ld4(pH), h1 = ld4(pH + 4);
        float4 wi[3][2], wh[3][2];
#pragma unroll
        for (int g = 0; g < 3; g++) {
            const float* pI = Wih + (size_t)(g * 256 + col0 + c) * 256 + k0 + kb;
            const float* pG = Whh + (size_t)(g * 256 + col0 + c) * 256 + k0 + kb;
            wi[g][0] = ld4(pI); wi[g][1] = ld4(pI + 4);
            wh[g][0] = ld4(pG); wh[g][1] = ld4(pG + 4);
        }
        __syncthreads();
        *(float4*)&Aag[GPOS(c, q0)] = a0; *(float4*)&Aag[GPOS(c, q1)] = a1;
        *(float4*)&Ahh[GPOS(c, q0)] = h0; *(float4*)&Ahh[GPOS(c, q1)] = h1;
#pragma unroll
        for (int g = 0; g < 3; g++) {
            *(float4*)&Bi[g][GPOS(c, q0)] = wi[g][0];
            *(float4*)&Bi[g][GPOS(c, q1)] = wi[g][1];
            *(float4*)&Bh[g][GPOS(c, q0)] = wh[g][0];
            *(float4*)&Bh[g][GPOS(c, q1)] = wh[g][1];
        }
        __syncthreads();
#pragma unroll
        for (int kq = 0; kq < 8; kq++) {
            float4 ar[4], hr[4];
#pragma unroll
            for (int i = 0; i < 4; i++) {
                ar[i] = ld4(&Aag[GPOS(ty * 4 + i, kq)]);
                hr[i] = ld4(&Ahh[GPOS(ty * 4 + i, kq)]);
            }
#pragma unroll
            for (int g = 0; g < 3; g++) {
#pragma unroll
                for (int j = 0; j < 4; j++) {
                    float4 bv = ld4(&Bi[g][GPOS(tx * 4 + j, kq)]);
                    float4 bw = ld4(&Bh[g][GPOS(tx * 4 + j, kq)]);
#pragma unroll
                    for (int i = 0; i < 4; i++) {
                        acc_i[g][i][j] += ar[i].x * bv.x + ar[i].y * bv.y +
                                          ar[i].z * bv.z + ar[i].w * bv.w;
                        acc_h[g][i][j] += hr[i].x * bw.x + hr[i].y * bw.y +
                                          hr[i].z * bw.z + hr[i].w * bw.w;
                    }
                }
            }
        }
    }
    // epilogue: biases + gates + mask
#pragma unroll
    for (int i = 0; i < 4; i++) {
        int r = row0 + ty * 4 + i;
        bool val = mask[r] > 0;
        float4 xv = ld4(&X[(size_t)r * 256 + col0 + tx * 4]);
        const float* xp = &xv.x;
        float o4[4];
#pragma unroll
        for (int j = 0; j < 4; j++) {
            int o = col0 + tx * 4 + j;
            float sr = (acc_i[0][i][j] + bih[o]) + (acc_h[0][i][j] + bhh[o]);
            float sz = (acc_i[1][i][j] + bih[o + 256]) + (acc_h[1][i][j] + bhh[o + 256]);
            float gn = acc_i[2][i][j] + bih[o + 512];
            float hn = acc_h[2][i][j] + bhh[o + 512];
            float rg = 1.f / (1.f + __expf(-sr));
            float zg = 1.f / (1.f + __expf(-sz));
            float pre = gn + rg * hn;
            float e2 = __expf(2.f * pre);
            float ng = 1.f - 2.f / (e2 + 1.f);       // tanh(pre)
            float h = (1.f - zg) * ng + zg * xp[j];
            o4[j] = val ? h : 0.f;
        }
        *(float4*)&out[(size_t)r * 256 + col0 + tx * 4] =
            make_float4(o4[0], o4[1], o4[2], o4[3]);
    }
}

// ---------------- launch ----------------

extern "C" void kernel_launch(void* const* d_in, const int* in_sizes, int n_in,
                              void* d_out, int out_size, void* d_ws, size_t ws_size,
                              hipStream_t stream) {
    const float* x   = (const float*)d_in[0];
    const int*   ei  = (const int*)d_in[1];
    const float* ew  = (const float*)d_in[2];
    const int*   msk = (const int*)d_in[3];
    const float* W   = (const float*)d_in[4];
    const float* Wih = (const float*)d_in[5];
    const float* Whh = (const float*)d_in[6];
    const float* bih = (const float*)d_in[7];
    const float* bhh = (const float*)d_in[8];
    float* out = (float*)d_out;

    // m lives in d_out (fully overwritten by gru_kernel at the end).
    float* m_buf = (float*)d_out;

    char* p = (char*)d_ws;
    float* aggb = (float*)p;  p += (size_t)Bn * Nn * Dn * sizeof(float);   // 32 MB
    int* cnt    = (int*)p;    p += (size_t)Bn * Nn * sizeof(int);
    int* off    = (int*)p;    p += (size_t)Bn * (Nn + 1) * sizeof(int);
    int* cursor = (int*)p;    p += (size_t)Bn * Nn * sizeof(int);
    int* csr_u  = (int*)p;    p += (size_t)Bn * En * sizeof(int);
    float* csr_w = (float*)p; p += (size_t)Bn * En * sizeof(float);

    hipMemsetAsync(cnt, 0, (size_t)Bn * Nn * sizeof(int), stream);
    hist_kernel<<<(Bn * En) / 256, 256, 0, stream>>>(ei, msk, cnt);
    scan_kernel<<<Bn, 256, 0, stream>>>(cnt, off, cursor);
    fill_kernel<<<(Bn * En) / 256, 256, 0, stream>>>(ei, msk, ew, cursor, csr_u, csr_w);
    gemm_m_kernel<<<dim3((Bn * Nn) / 64, Dn / 64), 256, 0, stream>>>(x, W, m_buf);
    agg_kernel<<<(Bn * Nn) / 4, 256, 0, stream>>>(m_buf, off, csr_u, csr_w, aggb);
    gru_kernel<<<dim3((Bn * Nn) / 64, Dn / 64), 256, 0, stream>>>(aggb, x, Wih, Whh,
                                                                  bih, bhh, msk, out);
}

// Round 2
// 208.541 us; speedup vs baseline: 4.8586x; 4.8586x over previous
//
#include <hip/hip_runtime.h>
#include <math.h>

#define Bn 8
#define Nn 4096
#define Dn 256
#define En 65536

typedef __bf16 bf8 __attribute__((ext_vector_type(8)));
typedef float f4 __attribute__((ext_vector_type(4)));

__device__ __forceinline__ float4 ld4(const float* p) { return *(const float4*)p; }

__device__ __forceinline__ unsigned short f2bf(float f) {
    union { float f; unsigned int u; } v; v.f = f;
    unsigned int r = v.u + 0x7fff + ((v.u >> 16) & 1);
    return (unsigned short)(r >> 16);
}
__device__ __forceinline__ float bf2f(unsigned short h) {
    union { unsigned int u; float f; } v; v.u = (unsigned int)h << 16;
    return v.f;
}

// ---------------- edge CSR build (by destination v, valid edges only) ----------------

__global__ __launch_bounds__(256) void hist_kernel(const int* __restrict__ ei,
                                                   const int* __restrict__ mask,
                                                   int* __restrict__ cnt) {
    int idx = blockIdx.x * 256 + threadIdx.x;
    int b = idx >> 16;
    int e = idx & 65535;
    const int* eb = ei + (size_t)b * 2 * En;
    int u = eb[e];
    int v = eb[En + e];
    const int* mb = mask + b * Nn;
    if (mb[u] > 0 && mb[v] > 0) atomicAdd(&cnt[b * Nn + v], 1);
}

__global__ __launch_bounds__(256) void scan_kernel(const int* __restrict__ cnt,
                                                   int* __restrict__ off,
                                                   int* __restrict__ cursor) {
    int b = blockIdx.x, t = threadIdx.x;
    __shared__ int chunk[256];
    int local[16];
    int s = 0;
    int base = b * Nn + t * 16;
#pragma unroll
    for (int i = 0; i < 16; i++) { local[i] = cnt[base + i]; s += local[i]; }
    chunk[t] = s;
    __syncthreads();
    for (int st = 1; st < 256; st <<= 1) {
        int v = (t >= st) ? chunk[t - st] : 0;
        __syncthreads();
        chunk[t] += v;
        __syncthreads();
    }
    int run = chunk[t] - s;
    int ob = b * (Nn + 1) + t * 16;
#pragma unroll
    for (int i = 0; i < 16; i++) {
        off[ob + i] = run;
        cursor[base + i] = run;
        run += local[i];
    }
    if (t == 255) off[b * (Nn + 1) + Nn] = run;
}

__global__ __launch_bounds__(256) void fill_kernel(const int* __restrict__ ei,
                                                   const int* __restrict__ mask,
                                                   const float* __restrict__ ew,
                                                   int* __restrict__ cursor,
                                                   int* __restrict__ csr_u,
                                                   float* __restrict__ csr_w) {
    int idx = blockIdx.x * 256 + threadIdx.x;
    int b = idx >> 16;
    int e = idx & 65535;
    const int* eb = ei + (size_t)b * 2 * En;
    int u = eb[e];
    int v = eb[En + e];
    const int* mb = mask + b * Nn;
    if (mb[u] > 0 && mb[v] > 0) {
        int pos = atomicAdd(&cursor[b * Nn + v], 1);
        csr_u[(size_t)b * En + pos] = u;
        csr_w[(size_t)b * En + pos] = ew[(size_t)b * En + e];
    }
}

// ---------------- bf16 casts ----------------

__global__ __launch_bounds__(256) void cast_x_kernel(const float* __restrict__ x,
                                                     unsigned short* __restrict__ xbf) {
    int i = (blockIdx.x * 256 + threadIdx.x) * 4;
    float4 v = ld4(x + i);
    ushort4 o;
    o.x = f2bf(v.x); o.y = f2bf(v.y); o.z = f2bf(v.z); o.w = f2bf(v.w);
    *(ushort4*)(xbf + i) = o;
}

__global__ __launch_bounds__(256) void cast_w_kernel(const float* __restrict__ Wih,
                                                     const float* __restrict__ Whh,
                                                     const float* __restrict__ W,
                                                     unsigned short* __restrict__ Wbi,
                                                     unsigned short* __restrict__ Wbh,
                                                     unsigned short* __restrict__ Wt) {
    int i = blockIdx.x * 256 + threadIdx.x;
    if (i < 196608) {
        Wbi[i] = f2bf(Wih[i]);
    } else if (i < 393216) {
        int j = i - 196608;
        Wbh[j] = f2bf(Whh[j]);
    } else {
        int j = i - 393216;          // [0, 65536): Wt[e][d] = W[d][e]
        int e = j >> 8, d = j & 255;
        Wt[j] = f2bf(W[d * 256 + e]);
    }
}

// ---------------- staging: global -> LDS, 16 rows x 32 k-elems (bf16), swizzled -----
// LDS layout: row-pair units of 128B; 16B chunk slot s within unit holds
// (r, c) with ((r&1)<<2 | c) = s ^ (unit&7).  global_load_lds dest = base + lane*16.

__device__ __forceinline__ void stage16(const unsigned short* __restrict__ g0,
                                        int R0, int k0, char* ldsregion, int lane) {
    int u = lane >> 3, s = lane & 7;
    int xx = s ^ (u & 7);
    int r = R0 + 2 * u + (xx >> 2);
    int c = xx & 3;
    const unsigned short* g = g0 + (size_t)r * 256 + k0 + c * 8;
    char* l = ldsregion + R0 * 64;
    __builtin_amdgcn_global_load_lds((const __attribute__((address_space(1))) void*)g,
                                     (__attribute__((address_space(3))) void*)l,
                                     16, 0, 0);
}

// frag read: row r (region-relative), k-chunk q = lane>>4
__device__ __forceinline__ bf8 fragld(const unsigned short* region, int r, int q) {
    int s = (((r & 1) << 2) | q) ^ ((r >> 1) & 7);
    return *(const bf8*)(region + (r >> 1) * 64 + s * 8);
}

// ---------------- m = x @ W  (bf16 MFMA, out bf16) ----------------

__global__ __launch_bounds__(256) void gemm_m_kernel(const unsigned short* __restrict__ xbf,
                                                     const unsigned short* __restrict__ Wt,
                                                     unsigned short* __restrict__ mbf) {
    __shared__ __align__(16) unsigned short lds[6144];   // A 4096 + B 2048 shorts
    const int t = threadIdx.x;
    const int lane = t & 63, w = t >> 6;
    const int wr = w >> 1, wc = w & 1;
    const int q = lane >> 4, c16 = lane & 15;
    const int row0 = blockIdx.x * 128, col0 = blockIdx.y * 64;

    f4 acc[4][2];
    f4 zz = {0.f, 0.f, 0.f, 0.f};
#pragma unroll
    for (int rt = 0; rt < 4; rt++)
#pragma unroll
        for (int ct = 0; ct < 2; ct++) acc[rt][ct] = zz;

    for (int k0 = 0; k0 < 256; k0 += 32) {
        __syncthreads();
        stage16(xbf + (size_t)row0 * 256, w * 32, k0, (char*)lds, lane);
        stage16(xbf + (size_t)row0 * 256, w * 32 + 16, k0, (char*)lds, lane);
        stage16(Wt + (size_t)col0 * 256, w * 16, k0, (char*)(lds + 4096), lane);
        __syncthreads();
        bf8 a[4];
#pragma unroll
        for (int rt = 0; rt < 4; rt++) a[rt] = fragld(lds, wr * 64 + rt * 16 + c16, q);
#pragma unroll
        for (int ct = 0; ct < 2; ct++) {
            bf8 b = fragld(lds + 4096, wc * 32 + ct * 16 + c16, q);
#pragma unroll
            for (int rt = 0; rt < 4; rt++)
                acc[rt][ct] = __builtin_amdgcn_mfma_f32_16x16x32_bf16(a[rt], b, acc[rt][ct], 0, 0, 0);
        }
    }
#pragma unroll
    for (int ct = 0; ct < 2; ct++) {
        int col = col0 + wc * 32 + ct * 16 + c16;
#pragma unroll
        for (int rt = 0; rt < 4; rt++) {
            int rbase = row0 + wr * 64 + rt * 16 + q * 4;
#pragma unroll
            for (int i = 0; i < 4; i++)
                mbf[(size_t)(rbase + i) * 256 + col] = f2bf(acc[rt][ct][i]);
        }
    }
}

// ---------------- agg[b,n,:] = sum_{edges -> n} w * m[b,u,:]  (bf16 in/out) ----------

__global__ __launch_bounds__(256) void agg_kernel(const unsigned short* __restrict__ M,
                                                  const int* __restrict__ off,
                                                  const int* __restrict__ csr_u,
                                                  const float* __restrict__ csr_w,
                                                  unsigned short* __restrict__ agg) {
    int wave = threadIdx.x >> 6, lane = threadIdx.x & 63;
    int g = blockIdx.x * 4 + wave;
    int b = g >> 12, n = g & 4095;
    int s = off[b * (Nn + 1) + n];
    int e = off[b * (Nn + 1) + n + 1];
    const int* cu = csr_u + (size_t)b * En;
    const float* cw = csr_w + (size_t)b * En;
    const unsigned short* Mb = M + (size_t)b * Nn * 256;
    float a0 = 0.f, a1 = 0.f, a2 = 0.f, a3 = 0.f;
    for (int j = s; j < e; j++) {
        int u = cu[j];
        float wv = cw[j];
        ushort4 mv = *(const ushort4*)(Mb + (size_t)u * 256 + lane * 4);
        a0 += wv * bf2f(mv.x); a1 += wv * bf2f(mv.y);
        a2 += wv * bf2f(mv.z); a3 += wv * bf2f(mv.w);
    }
    ushort4 o;
    o.x = f2bf(a0); o.y = f2bf(a1); o.z = f2bf(a2); o.w = f2bf(a3);
    *(ushort4*)(agg + (size_t)g * 256 + lane * 4) = o;
}

// ---------------- fused GRU: 6 MFMA GEMM tiles + gates + mask ----------------
// block tile 128 rows x 64 cols; 4 waves in 2x2; wave = 64r x 32c; BK=32.

__global__ __launch_bounds__(256, 2) void gru_kernel(const unsigned short* __restrict__ aggb,
                                                     const unsigned short* __restrict__ xbf,
                                                     const unsigned short* __restrict__ Wbi,
                                                     const unsigned short* __restrict__ Wbh,
                                                     const float* __restrict__ X,
                                                     const float* __restrict__ bih,
                                                     const float* __restrict__ bhh,
                                                     const int* __restrict__ mask,
                                                     float* __restrict__ out) {
    __shared__ __align__(16) unsigned short lds[20480];  // Aag 4096 | Ah 4096 | B 6*2048
    const int t = threadIdx.x;
    const int lane = t & 63, w = t >> 6;
    const int wr = w >> 1, wc = w & 1;
    const int q = lane >> 4, c16 = lane & 15;
    const int row0 = blockIdx.x * 128, col0 = blockIdx.y * 64;

    f4 acci[3][4][2], acch[3][4][2];
    f4 zz = {0.f, 0.f, 0.f, 0.f};
#pragma unroll
    for (int g = 0; g < 3; g++)
#pragma unroll
        for (int rt = 0; rt < 4; rt++)
#pragma unroll
            for (int ct = 0; ct < 2; ct++) { acci[g][rt][ct] = zz; acch[g][rt][ct] = zz; }

    for (int k0 = 0; k0 < 256; k0 += 32) {
        __syncthreads();
        stage16(aggb + (size_t)row0 * 256, w * 32, k0, (char*)lds, lane);
        stage16(aggb + (size_t)row0 * 256, w * 32 + 16, k0, (char*)lds, lane);
        stage16(xbf + (size_t)row0 * 256, w * 32, k0, (char*)(lds + 4096), lane);
        stage16(xbf + (size_t)row0 * 256, w * 32 + 16, k0, (char*)(lds + 4096), lane);
#pragma unroll
        for (int j = 0; j < 6; j++) {
            int id = w * 6 + j;
            int m = id >> 2, C0 = (id & 3) * 16;
            const unsigned short* wb = (m < 3)
                ? (Wbi + ((size_t)m * 256 + col0) * 256)
                : (Wbh + ((size_t)(m - 3) * 256 + col0) * 256);
            stage16(wb, C0, k0, (char*)(lds + 8192) + m * 4096, lane);
        }
        __syncthreads();
        bf8 aag[4], ah[4];
#pragma unroll
        for (int rt = 0; rt < 4; rt++) {
            int r = wr * 64 + rt * 16 + c16;
            aag[rt] = fragld(lds, r, q);
            ah[rt] = fragld(lds + 4096, r, q);
        }
#pragma unroll
        for (int ct = 0; ct < 2; ct++) {
            int cc = wc * 32 + ct * 16 + c16;
#pragma unroll
            for (int g = 0; g < 3; g++) {
                bf8 bi = fragld(lds + 8192 + g * 2048, cc, q);
                bf8 bh = fragld(lds + 8192 + (3 + g) * 2048, cc, q);
#pragma unroll
                for (int rt = 0; rt < 4; rt++) {
                    acci[g][rt][ct] =
                        __builtin_amdgcn_mfma_f32_16x16x32_bf16(aag[rt], bi, acci[g][rt][ct], 0, 0, 0);
                    acch[g][rt][ct] =
                        __builtin_amdgcn_mfma_f32_16x16x32_bf16(ah[rt], bh, acch[g][rt][ct], 0, 0, 0);
                }
            }
        }
    }
    // epilogue: biases + gates + mask
#pragma unroll
    for (int ct = 0; ct < 2; ct++) {
        int col = col0 + wc * 32 + ct * 16 + c16;
        float bir = bih[col], biz = bih[col + 256], bin = bih[col + 512];
        float bhr = bhh[col], bhz = bhh[col + 256], bhn = bhh[col + 512];
#pragma unroll
        for (int rt = 0; rt < 4; rt++) {
            int rbase = row0 + wr * 64 + rt * 16 + q * 4;
#pragma unroll
            for (int i = 0; i < 4; i++) {
                int row = rbase + i;
                float sr = acci[0][rt][ct][i] + bir + acch[0][rt][ct][i] + bhr;
                float sz = acci[1][rt][ct][i] + biz + acch[1][rt][ct][i] + bhz;
                float gn = acci[2][rt][ct][i] + bin;
                float hn = acch[2][rt][ct][i] + bhn;
                float rg = 1.f / (1.f + __expf(-sr));
                float zg = 1.f / (1.f + __expf(-sz));
                float pre = gn + rg * hn;
                float e2 = __expf(2.f * pre);
                float ng = 1.f - 2.f / (e2 + 1.f);
                float xv = X[(size_t)row * 256 + col];
                float h = (1.f - zg) * ng + zg * xv;
                out[(size_t)row * 256 + col] = (mask[row] > 0) ? h : 0.f;
            }
        }
    }
}

// ---------------- launch ----------------

extern "C" void kernel_launch(void* const* d_in, const int* in_sizes, int n_in,
                              void* d_out, int out_size, void* d_ws, size_t ws_size,
                              hipStream_t stream) {
    const float* x   = (const float*)d_in[0];
    const int*   ei  = (const int*)d_in[1];
    const float* ew  = (const float*)d_in[2];
    const int*   msk = (const int*)d_in[3];
    const float* W   = (const float*)d_in[4];
    const float* Wih = (const float*)d_in[5];
    const float* Whh = (const float*)d_in[6];
    const float* bih = (const float*)d_in[7];
    const float* bhh = (const float*)d_in[8];
    float* out = (float*)d_out;

    // m (bf16) lives in the front half of d_out (32MB fp32 region, fully
    // overwritten by gru_kernel's epilogue afterwards).
    unsigned short* mbf = (unsigned short*)d_out;

    char* p = (char*)d_ws;
    unsigned short* aggb = (unsigned short*)p; p += (size_t)Bn * Nn * Dn * 2;  // 16 MB
    unsigned short* xbf  = (unsigned short*)p; p += (size_t)Bn * Nn * Dn * 2;  // 16 MB
    unsigned short* Wbi  = (unsigned short*)p; p += (size_t)3 * Dn * Dn * 2;
    unsigned short* Wbh  = (unsigned short*)p; p += (size_t)3 * Dn * Dn * 2;
    unsigned short* Wt   = (unsigned short*)p; p += (size_t)Dn * Dn * 2;
    int* cnt    = (int*)p;    p += (size_t)Bn * Nn * sizeof(int);
    int* off    = (int*)p;    p += (size_t)Bn * (Nn + 1) * sizeof(int);
    int* cursor = (int*)p;    p += (size_t)Bn * Nn * sizeof(int);
    int* csr_u  = (int*)p;    p += (size_t)Bn * En * sizeof(int);
    float* csr_w = (float*)p; p += (size_t)Bn * En * sizeof(float);

    hipMemsetAsync(cnt, 0, (size_t)Bn * Nn * sizeof(int), stream);
    hist_kernel<<<(Bn * En) / 256, 256, 0, stream>>>(ei, msk, cnt);
    scan_kernel<<<Bn, 256, 0, stream>>>(cnt, off, cursor);
    fill_kernel<<<(Bn * En) / 256, 256, 0, stream>>>(ei, msk, ew, cursor, csr_u, csr_w);
    cast_x_kernel<<<(Bn * Nn * Dn) / 1024, 256, 0, stream>>>(x, xbf);
    cast_w_kernel<<<1792, 256, 0, stream>>>(Wih, Whh, W, Wbi, Wbh, Wt);
    gemm_m_kernel<<<dim3(256, 4), 256, 0, stream>>>(xbf, Wt, mbf);
    agg_kernel<<<(Bn * Nn) / 4, 256, 0, stream>>>(mbf, off, csr_u, csr_w, aggb);
    gru_kernel<<<dim3(256, 4), 256, 0, stream>>>(aggb, xbf, Wbi, Wbh, x, bih, bhh, msk, out);
}